// Round 1
// baseline (1475.487 us; speedup 1.0000x reference)
//
#include <hip/hip_runtime.h>
#include <stdint.h>

#define D_FEAT 128
#define TOPK   128

// ---------------- squared norms ----------------
__global__ __launch_bounds__(256) void sqnorm_kernel(const float* __restrict__ X,
                                                     float* __restrict__ out, int rows) {
    int r = blockIdx.x * 256 + threadIdx.x;
    if (r >= rows) return;
    const float4* p = (const float4*)(X + (size_t)r * D_FEAT);
    float s = 0.f;
    #pragma unroll
    for (int i = 0; i < D_FEAT / 4; ++i) {
        float4 v = p[i];
        s += v.x * v.x + v.y * v.y + v.z * v.z + v.w * v.w;
    }
    out[r] = s;
}

// ---------------- distance GEMM: dist2 = max(x2 + y2 - 2*Q.D^T, 0) ----------------
#define BM 64
#define BN 64
#define BK 64
#define LDP 68   // padded LDS stride (68*4B = 272B, 16B-aligned, breaks bank conflicts)

__global__ __launch_bounds__(256) void dist_kernel(const float* __restrict__ Q,
                                                   const float* __restrict__ Dta,
                                                   const float* __restrict__ x2,
                                                   const float* __restrict__ y2,
                                                   float* __restrict__ out,
                                                   int q0, int N) {
    __shared__ float As[BK][LDP];   // k-major: As[k][m]
    __shared__ float Bs[BK][LDP];   // k-major: Bs[k][n]
    const int tid   = threadIdx.x;
    const int jbase = blockIdx.x * BN;          // data-point tile base
    const int mrow  = blockIdx.y * BM;          // row within chunk (buffer row)
    const int qbase = q0 + mrow;                // absolute query row
    const int tx = tid & 15, ty = tid >> 4;

    float acc[4][4];
    #pragma unroll
    for (int i = 0; i < 4; ++i)
        #pragma unroll
        for (int j = 0; j < 4; ++j) acc[i][j] = 0.f;

    for (int kt = 0; kt < D_FEAT; kt += BK) {
        // stage 64x64 of A and B, transposed to k-major
        #pragma unroll
        for (int it = 0; it < 4; ++it) {
            int r  = it * 16 + (tid >> 4);      // 0..63
            int c4 = tid & 15;                  // 0..15 (float4 column)
            float4 va = *(const float4*)(&Q  [(size_t)(qbase + r) * D_FEAT + kt + c4 * 4]);
            float4 vb = *(const float4*)(&Dta[(size_t)(jbase + r) * D_FEAT + kt + c4 * 4]);
            As[c4 * 4 + 0][r] = va.x; As[c4 * 4 + 1][r] = va.y;
            As[c4 * 4 + 2][r] = va.z; As[c4 * 4 + 3][r] = va.w;
            Bs[c4 * 4 + 0][r] = vb.x; Bs[c4 * 4 + 1][r] = vb.y;
            Bs[c4 * 4 + 2][r] = vb.z; Bs[c4 * 4 + 3][r] = vb.w;
        }
        __syncthreads();
        #pragma unroll 8
        for (int k = 0; k < BK; ++k) {
            float4 a = *(const float4*)(&As[k][ty * 4]);
            float4 b = *(const float4*)(&Bs[k][tx * 4]);
            float av[4] = {a.x, a.y, a.z, a.w};
            float bv[4] = {b.x, b.y, b.z, b.w};
            #pragma unroll
            for (int i = 0; i < 4; ++i)
                #pragma unroll
                for (int j = 0; j < 4; ++j)
                    acc[i][j] = fmaf(av[i], bv[j], acc[i][j]);
        }
        __syncthreads();
    }

    // epilogue: dist2 = max(x2 + y2 - 2*dot, 0)
    float4 y2v = *(const float4*)(&y2[jbase + tx * 4]);
    float y2a[4] = {y2v.x, y2v.y, y2v.z, y2v.w};
    #pragma unroll
    for (int i = 0; i < 4; ++i) {
        float xv = x2[qbase + ty * 4 + i];
        float4 o;
        o.x = fmaxf(xv + y2a[0] - 2.f * acc[i][0], 0.f);
        o.y = fmaxf(xv + y2a[1] - 2.f * acc[i][1], 0.f);
        o.z = fmaxf(xv + y2a[2] - 2.f * acc[i][2], 0.f);
        o.w = fmaxf(xv + y2a[3] - 2.f * acc[i][3], 0.f);
        *(float4*)(&out[(size_t)(mrow + ty * 4 + i) * N + jbase + tx * 4]) = o;
    }
}

// ---------------- per-query selection + vote ----------------
// One block of 1024 threads per query row. Row cached in 64 regs/thread.
// Binary radix-select over uint32 keys (nonneg float bits are order-monotone).
#define SEL_T 1024
#define VPT   64        // 65536 / 1024
#define MAXT  4096      // max ties tracked at the cutoff value

__global__ __launch_bounds__(SEL_T) void select_kernel(const float* __restrict__ dist,
                                                       const float* __restrict__ labels,
                                                       int* __restrict__ out,
                                                       int q0, int N, int n_total, int out_size) {
    const int tid = threadIdx.x;
    const float* row = dist + (size_t)blockIdx.x * N;

    uint32_t keys[VPT];
    #pragma unroll
    for (int i = 0; i < VPT; ++i)
        keys[i] = __float_as_uint(row[(size_t)i * SEL_T + tid]);

    __shared__ unsigned int red[SEL_T / 64];
    __shared__ unsigned int bcast;

    uint32_t prefix = 0;
    uint32_t kth    = TOPK;   // 1-based rank to find within current candidate group

    for (int bit = 31; bit >= 0; --bit) {
        uint32_t known_mask = (bit == 31) ? 0u : (0xFFFFFFFFu << (bit + 1));
        uint32_t bitm = 1u << bit;
        uint32_t cnt = 0;
        #pragma unroll
        for (int i = 0; i < VPT; ++i) {
            uint32_t key = keys[i];
            cnt += (((key & known_mask) == prefix) && ((key & bitm) == 0u)) ? 1u : 0u;
        }
        // block reduce
        #pragma unroll
        for (int off = 32; off > 0; off >>= 1)
            cnt += __shfl_down(cnt, off, 64);
        int wid = tid >> 6;
        if ((tid & 63) == 0) red[wid] = cnt;
        __syncthreads();
        if (tid == 0) {
            unsigned int tot = 0;
            #pragma unroll
            for (int w = 0; w < SEL_T / 64; ++w) tot += red[w];
            bcast = tot;
        }
        __syncthreads();
        uint32_t total0 = bcast;
        if (kth > total0) { kth -= total0; prefix |= bitm; }
        // (red/bcast reuse next pass is protected by the two syncs above)
    }

    const uint32_t tau = prefix;     // exact key of the 128th smallest
    const uint32_t t_take = kth;     // how many tau-valued entries belong to top-128

    __shared__ unsigned int tie_cnt;
    __shared__ unsigned int votes_sh;
    __shared__ unsigned int ties[MAXT];
    if (tid == 0) { tie_cnt = 0; votes_sh = 0; }
    __syncthreads();

    uint32_t votes = 0;
    #pragma unroll
    for (int i = 0; i < VPT; ++i) {
        uint32_t key = keys[i];
        if (key < tau) {
            int j = i * SEL_T + tid;
            votes += (labels[j] > 0.5f) ? 1u : 0u;
        } else if (key == tau) {
            int j = i * SEL_T + tid;
            unsigned int lab = (labels[j] > 0.5f) ? 0x80000000u : 0u;
            unsigned int p = atomicAdd(&tie_cnt, 1u);
            if (p < MAXT) ties[p] = (unsigned int)j | lab;
        }
    }
    #pragma unroll
    for (int off = 32; off > 0; off >>= 1)
        votes += __shfl_down(votes, off, 64);
    if ((tid & 63) == 0) atomicAdd(&votes_sh, votes);
    __syncthreads();

    unsigned int m = tie_cnt; if (m > MAXT) m = MAXT;
    uint32_t tv = 0;
    for (unsigned int e = tid; e < m; e += SEL_T) {
        unsigned int me = ties[e];
        unsigned int myidx = me & 0x7FFFFFFFu;
        unsigned int rank = 0;
        for (unsigned int f = 0; f < m; ++f)
            rank += ((ties[f] & 0x7FFFFFFFu) < myidx) ? 1u : 0u;
        if (rank < t_take && (me & 0x80000000u)) tv++;
    }
    if (tv) atomicAdd(&votes_sh, tv);
    __syncthreads();

    if (tid == 0) {
        unsigned int v1 = votes_sh;                 // votes for class 1
        int qi = q0 + blockIdx.x;
        out[qi] = (2u * v1 > (unsigned int)TOPK) ? 1 : 0;   // tie (64/64) -> class 0
        if (qi == 0 && out_size > n_total) out[n_total] = 0; // second tuple element
    }
}

// ---------------- host ----------------
extern "C" void kernel_launch(void* const* d_in, const int* in_sizes, int n_in,
                              void* d_out, int out_size, void* d_ws, size_t ws_size,
                              hipStream_t stream) {
    const float* Q   = (const float*)d_in[0];
    const float* Dta = (const float*)d_in[1];
    const float* L   = (const float*)d_in[2];
    const int n = in_sizes[0] / D_FEAT;    // 2048
    const int N = in_sizes[1] / D_FEAT;    // 65536
    int* out = (int*)d_out;

    char* ws = (char*)d_ws;
    size_t off = 0;
    float* y2 = (float*)(ws + off); off += (((size_t)N * sizeof(float)) + 255) & ~(size_t)255;
    float* x2 = (float*)(ws + off); off += (((size_t)n * sizeof(float)) + 255) & ~(size_t)255;
    float* distbuf = (float*)(ws + off);
    size_t avail = (ws_size > off) ? (ws_size - off) : 0;
    long maxQ = (long)(avail / ((size_t)N * sizeof(float)));
    int chunkQ;
    if (maxQ >= n) chunkQ = n;
    else { chunkQ = (int)((maxQ / 64) * 64); if (chunkQ < 64) chunkQ = 64; }

    sqnorm_kernel<<<dim3((N + 255) / 256), dim3(256), 0, stream>>>(Dta, y2, N);
    sqnorm_kernel<<<dim3((n + 255) / 256), dim3(256), 0, stream>>>(Q, x2, n);

    for (int q0 = 0; q0 < n; q0 += chunkQ) {
        int q = n - q0; if (q > chunkQ) q = chunkQ;
        dim3 grid(N / BN, q / BM);
        dist_kernel<<<grid, dim3(256), 0, stream>>>(Q, Dta, x2, y2, distbuf, q0, N);
        select_kernel<<<dim3(q), dim3(SEL_T), 0, stream>>>(distbuf, L, out, q0, N, n, out_size);
    }
}

// Round 2
// 840.670 us; speedup vs baseline: 1.7551x; 1.7551x over previous
//
#include <hip/hip_runtime.h>
#include <stdint.h>

#define D_FEAT 128
#define TOPK   128

// ---------------- squared norms ----------------
__global__ __launch_bounds__(256) void sqnorm_kernel(const float* __restrict__ X,
                                                     float* __restrict__ out, int rows) {
    int r = blockIdx.x * 256 + threadIdx.x;
    if (r >= rows) return;
    const float4* p = (const float4*)(X + (size_t)r * D_FEAT);
    float s = 0.f;
    #pragma unroll
    for (int i = 0; i < D_FEAT / 4; ++i) {
        float4 v = p[i];
        s += v.x * v.x + v.y * v.y + v.z * v.z + v.w * v.w;
    }
    out[r] = s;
}

// ---------------- distance GEMM: dist2 = max(x2 + y2 - 2*Q.D^T, 0) ----------------
#define BM 64
#define BN 64
#define BK 64
#define LDP 68   // padded LDS stride

__global__ __launch_bounds__(256) void dist_kernel(const float* __restrict__ Q,
                                                   const float* __restrict__ Dta,
                                                   const float* __restrict__ x2,
                                                   const float* __restrict__ y2,
                                                   float* __restrict__ out,
                                                   int q0, int N) {
    __shared__ float As[BK][LDP];   // k-major: As[k][m]
    __shared__ float Bs[BK][LDP];   // k-major: Bs[k][n]
    const int tid   = threadIdx.x;
    const int jbase = blockIdx.x * BN;
    const int mrow  = blockIdx.y * BM;
    const int qbase = q0 + mrow;
    const int tx = tid & 15, ty = tid >> 4;

    float acc[4][4];
    #pragma unroll
    for (int i = 0; i < 4; ++i)
        #pragma unroll
        for (int j = 0; j < 4; ++j) acc[i][j] = 0.f;

    for (int kt = 0; kt < D_FEAT; kt += BK) {
        #pragma unroll
        for (int it = 0; it < 4; ++it) {
            int r  = it * 16 + (tid >> 4);
            int c4 = tid & 15;
            float4 va = *(const float4*)(&Q  [(size_t)(qbase + r) * D_FEAT + kt + c4 * 4]);
            float4 vb = *(const float4*)(&Dta[(size_t)(jbase + r) * D_FEAT + kt + c4 * 4]);
            As[c4 * 4 + 0][r] = va.x; As[c4 * 4 + 1][r] = va.y;
            As[c4 * 4 + 2][r] = va.z; As[c4 * 4 + 3][r] = va.w;
            Bs[c4 * 4 + 0][r] = vb.x; Bs[c4 * 4 + 1][r] = vb.y;
            Bs[c4 * 4 + 2][r] = vb.z; Bs[c4 * 4 + 3][r] = vb.w;
        }
        __syncthreads();
        #pragma unroll 8
        for (int k = 0; k < BK; ++k) {
            float4 a = *(const float4*)(&As[k][ty * 4]);
            float4 b = *(const float4*)(&Bs[k][tx * 4]);
            float av[4] = {a.x, a.y, a.z, a.w};
            float bv[4] = {b.x, b.y, b.z, b.w};
            #pragma unroll
            for (int i = 0; i < 4; ++i)
                #pragma unroll
                for (int j = 0; j < 4; ++j)
                    acc[i][j] = fmaf(av[i], bv[j], acc[i][j]);
        }
        __syncthreads();
    }

    float4 y2v = *(const float4*)(&y2[jbase + tx * 4]);
    float y2a[4] = {y2v.x, y2v.y, y2v.z, y2v.w};
    #pragma unroll
    for (int i = 0; i < 4; ++i) {
        float xv = x2[qbase + ty * 4 + i];
        float4 o;
        o.x = fmaxf(xv + y2a[0] - 2.f * acc[i][0], 0.f);
        o.y = fmaxf(xv + y2a[1] - 2.f * acc[i][1], 0.f);
        o.z = fmaxf(xv + y2a[2] - 2.f * acc[i][2], 0.f);
        o.w = fmaxf(xv + y2a[3] - 2.f * acc[i][3], 0.f);
        *(float4*)(&out[(size_t)(mrow + ty * 4 + i) * N + jbase + tx * 4]) = o;
    }
}

// ---------------- per-query selection + vote (v2) ----------------
// One 1024-thread block per query. 16-bit monotone keys (float_bits >> 15)
// packed 2-per-VGPR (32 regs, no spill). 16-pass binary search on the value
// domain (1 compare/key/pass, 1 barrier/pass via double-buffered reduce).
// Exact tie resolution at the 16-bit cutoff via (f32 value, index) ranking.
#define SEL_T 1024
#define VPT   64
#define NPK   (VPT / 2)          // 32 packed regs
#define CAP   7680               // tie-candidate cap (61.4 KB LDS)

__global__ __launch_bounds__(SEL_T, 4) void select2_kernel(const float* __restrict__ dist,
                                                           const float* __restrict__ labels,
                                                           int* __restrict__ out,
                                                           int q0, int N, int n_total, int out_size) {
    const int tid = threadIdx.x;
    const float* row = dist + (size_t)blockIdx.x * N;

    // ---- load + build packed 16-bit keys ----
    uint32_t pk[NPK];
    #pragma unroll
    for (int i = 0; i < VPT / 4; ++i) {
        float4 v = *(const float4*)(row + i * 4096 + tid * 4);
        uint32_t k0 = __float_as_uint(v.x) >> 15;   // bits 30:15, monotone for x>=0
        uint32_t k1 = __float_as_uint(v.y) >> 15;
        uint32_t k2 = __float_as_uint(v.z) >> 15;
        uint32_t k3 = __float_as_uint(v.w) >> 15;
        pk[i * 2 + 0] = k0 | (k1 << 16);
        pk[i * 2 + 1] = k2 | (k3 << 16);
    }

    __shared__ unsigned int red[2][SEL_T / 64];
    __shared__ unsigned int mcnt, votes_sh;
    __shared__ float        cval[CAP];
    __shared__ unsigned int ckey[CAP];   // idx | (label<<31)

    // ---- binary search for tau: smallest t with count(key < t) >= TOPK ----
    uint32_t lo = 0, hi = 65536, base = 0;
    const int wid = tid >> 6;
    #pragma unroll
    for (int pass = 0; pass < 16; ++pass) {
        uint32_t mid = (lo + hi) >> 1;
        uint32_t cnt = 0;
        #pragma unroll
        for (int r = 0; r < NPK; ++r) {
            uint32_t p = pk[r];
            cnt += ((p & 0xFFFFu) < mid) ? 1u : 0u;
            cnt += ((p >> 16)     < mid) ? 1u : 0u;
        }
        #pragma unroll
        for (int off = 32; off > 0; off >>= 1)
            cnt += __shfl_down(cnt, off, 64);
        if ((tid & 63) == 0) red[pass & 1][wid] = cnt;
        __syncthreads();
        uint32_t tot = 0;
        #pragma unroll
        for (int w = 0; w < SEL_T / 64; ++w) tot += red[pass & 1][w];
        if (tot >= TOPK) hi = mid;
        else             { lo = mid; base = tot; }
    }
    const uint32_t tau    = lo;            // key16 of the 128th smallest
    const uint32_t t_take = TOPK - base;   // how many tau-ties belong to top-128

    if (tid == 0) { mcnt = 0; votes_sh = 0; }
    __syncthreads();

    // ---- vote below tau; gather tau-ties with exact f32 values ----
    uint32_t votes = 0;
    #pragma unroll
    for (int r = 0; r < NPK; ++r) {
        uint32_t p = pk[r];
        #pragma unroll
        for (int h = 0; h < 2; ++h) {
            uint32_t key = (h == 0) ? (p & 0xFFFFu) : (p >> 16);
            if (key <= tau) {
                int i = r >> 1;               // float4 group
                int q = r & 1;                // which packed pair
                int j = i * 4096 + tid * 4 + q * 2 + h;
                if (key < tau) {
                    votes += (labels[j] > 0.5f) ? 1u : 0u;
                } else {
                    unsigned int lab = (labels[j] > 0.5f) ? 0x80000000u : 0u;
                    unsigned int e = atomicAdd(&mcnt, 1u);
                    if (e < CAP) { cval[e] = row[j]; ckey[e] = (unsigned int)j | lab; }
                }
            }
        }
    }
    #pragma unroll
    for (int off = 32; off > 0; off >>= 1)
        votes += __shfl_down(votes, off, 64);
    if ((tid & 63) == 0 && votes) atomicAdd(&votes_sh, votes);
    __syncthreads();

    // ---- rank tau-ties by (f32 value, index); take first t_take ----
    unsigned int m = mcnt; if (m > CAP) m = CAP;
    for (unsigned int e = tid; e < m; e += SEL_T) {
        float        ve = cval[e];
        unsigned int ke = ckey[e];
        unsigned int ie = ke & 0x7FFFFFFFu;
        unsigned int rank = 0;
        for (unsigned int f = 0; f < m; ++f) {
            float        vf = cval[f];
            unsigned int jf = ckey[f] & 0x7FFFFFFFu;
            rank += (vf < ve || (vf == ve && jf < ie)) ? 1u : 0u;
        }
        if (rank < t_take && (ke & 0x80000000u)) atomicAdd(&votes_sh, 1u);
    }
    __syncthreads();

    if (tid == 0) {
        unsigned int v1 = votes_sh;
        int qi = q0 + blockIdx.x;
        out[qi] = (v1 > TOPK / 2) ? 1 : 0;      // 64/64 tie -> class 0
        if (qi == 0 && out_size > n_total) out[n_total] = 0;
    }
}

// ---------------- host ----------------
extern "C" void kernel_launch(void* const* d_in, const int* in_sizes, int n_in,
                              void* d_out, int out_size, void* d_ws, size_t ws_size,
                              hipStream_t stream) {
    const float* Q   = (const float*)d_in[0];
    const float* Dta = (const float*)d_in[1];
    const float* L   = (const float*)d_in[2];
    const int n = in_sizes[0] / D_FEAT;    // 2048
    const int N = in_sizes[1] / D_FEAT;    // 65536
    int* out = (int*)d_out;

    char* ws = (char*)d_ws;
    size_t off = 0;
    float* y2 = (float*)(ws + off); off += (((size_t)N * sizeof(float)) + 255) & ~(size_t)255;
    float* x2 = (float*)(ws + off); off += (((size_t)n * sizeof(float)) + 255) & ~(size_t)255;
    float* distbuf = (float*)(ws + off);
    size_t avail = (ws_size > off) ? (ws_size - off) : 0;
    long maxQ = (long)(avail / ((size_t)N * sizeof(float)));
    int chunkQ;
    if (maxQ >= n) chunkQ = n;
    else { chunkQ = (int)((maxQ / 64) * 64); if (chunkQ < 64) chunkQ = 64; }

    sqnorm_kernel<<<dim3((N + 255) / 256), dim3(256), 0, stream>>>(Dta, y2, N);
    sqnorm_kernel<<<dim3((n + 255) / 256), dim3(256), 0, stream>>>(Q, x2, n);

    for (int q0 = 0; q0 < n; q0 += chunkQ) {
        int q = n - q0; if (q > chunkQ) q = chunkQ;
        dim3 grid(N / BN, q / BM);
        dist_kernel<<<grid, dim3(256), 0, stream>>>(Q, Dta, x2, y2, distbuf, q0, N);
        select2_kernel<<<dim3(q), dim3(SEL_T), 0, stream>>>(distbuf, L, out, q0, N, n, out_size);
    }
}